// Round 6
// baseline (3764.856 us; speedup 1.0000x reference)
//
#include <hip/hip_runtime.h>
#include <math.h>

#define N_NODES 200000
#define N_EDGES 3200000
#define M_SEL   100000
#define NEX     32
#define NT      11
#define CH      32
#define HID     1024
#define NL      8
#define BN_EPS  1e-5f

#define BSHIFT  9
#define BSIZE   512
#define KB      391
#define PAYMASK 0x3FFFF

// bf16 helpers (RNE)
__device__ __forceinline__ unsigned bf16_bits(float f) {
  unsigned u = __float_as_uint(f);
  return (u + 0x7fffu + ((u >> 16) & 1u)) >> 16;
}
__device__ __forceinline__ unsigned pack_bf2(float lo, float hi) {
  return bf16_bits(lo) | (bf16_bits(hi) << 16);
}
#define BF_LO(u) __uint_as_float((u) << 16)
#define BF_HI(u) __uint_as_float((u) & 0xffff0000u)

// ---------------------------------------------------------------------------
// CSR build (radix-partition, from R5 — unchanged)
// ---------------------------------------------------------------------------
__global__ void __launch_bounds__(256) bin_count_kernel(
    const int* __restrict__ src, const int* __restrict__ dst,
    int* __restrict__ bcnt_in, int* __restrict__ bcnt_out) {
  __shared__ int h_in[KB], h_out[KB];
  int tid = threadIdx.x;
  for (int i = tid; i < KB; i += 256) { h_in[i] = 0; h_out[i] = 0; }
  __syncthreads();
  for (int e = blockIdx.x * 256 + tid; e < N_EDGES; e += gridDim.x * 256) {
    atomicAdd(&h_in[dst[e] >> BSHIFT], 1);
    atomicAdd(&h_out[src[e] >> BSHIFT], 1);
  }
  __syncthreads();
  for (int b = tid; b < KB; b += 256) {
    if (h_in[b])  atomicAdd(&bcnt_in[b], h_in[b]);
    if (h_out[b]) atomicAdd(&bcnt_out[b], h_out[b]);
  }
}

__global__ void __launch_bounds__(256) bucket_scan_kernel(
    const int* __restrict__ bcnt_in, int* __restrict__ boff_in, int* __restrict__ gcur_in,
    const int* __restrict__ bcnt_out, int* __restrict__ boff_out, int* __restrict__ gcur_out) {
  __shared__ int s[512];
  __shared__ int wtot[4];
  int tid = threadIdx.x;
  int lane = tid & 63, wid = tid >> 6;
  for (int dir = 0; dir < 2; dir++) {
    const int* bcnt = dir ? bcnt_out : bcnt_in;
    int* boff = dir ? boff_out : boff_in;
    int* gcur = dir ? gcur_out : gcur_in;
    int i0 = 2 * tid, i1 = 2 * tid + 1;
    int a0 = (i0 < KB) ? bcnt[i0] : 0;
    int a1 = (i1 < KB) ? bcnt[i1] : 0;
    int pair = a0 + a1;
    int incl = pair;
#pragma unroll
    for (int o = 1; o < 64; o <<= 1) { int t = __shfl_up(incl, o); if (lane >= o) incl += t; }
    if (lane == 63) wtot[wid] = incl;
    __syncthreads();
    if (tid == 0) { int r = 0; for (int w = 0; w < 4; w++) { int v = wtot[w]; wtot[w] = r; r += v; } }
    __syncthreads();
    int exclp = incl - pair + wtot[wid];
    s[i0] = exclp;
    s[i1] = exclp + a0;
    __syncthreads();
    for (int b = tid; b < KB; b += 256) { boff[b] = s[b]; gcur[b] = s[b]; }
    if (i0 == KB - 1) boff[KB] = s[i0] + a0;
    if (i1 == KB - 1) boff[KB] = s[i1] + a1;
    __syncthreads();
  }
}

__global__ void __launch_bounds__(256) stage_kernel(
    const int* __restrict__ src, const int* __restrict__ dst,
    int* __restrict__ gcur_in, unsigned* __restrict__ staging_in,
    int* __restrict__ gcur_out, unsigned* __restrict__ staging_out) {
  __shared__ int cnt[KB], cur[KB];
  int tid = threadIdx.x;
  int dir = blockIdx.y;
  const int* key = dir ? src : dst;
  const int* pay = dir ? dst : src;
  int* gcur = dir ? gcur_out : gcur_in;
  unsigned* staging = dir ? staging_out : staging_in;
  for (int i = tid; i < KB; i += 256) cnt[i] = 0;
  __syncthreads();
  int e0 = blockIdx.x * 4096;
#pragma unroll
  for (int j = 0; j < 16; j++) {
    int e = e0 + j * 256 + tid;
    if (e < N_EDGES) atomicAdd(&cnt[key[e] >> BSHIFT], 1);
  }
  __syncthreads();
  for (int b = tid; b < KB; b += 256) {
    int c = cnt[b];
    cur[b] = c ? atomicAdd(&gcur[b], c) : 0;
  }
  __syncthreads();
#pragma unroll
  for (int j = 0; j < 16; j++) {
    int e = e0 + j * 256 + tid;
    if (e < N_EDGES) {
      int k = key[e];
      int b = k >> BSHIFT;
      int p = atomicAdd(&cur[b], 1);
      staging[p] = ((unsigned)(k & (BSIZE - 1)) << 18) | (unsigned)pay[e];
    }
  }
}

__global__ void __launch_bounds__(256) build_kernel(
    const unsigned* __restrict__ staging_in, const int* __restrict__ boff_in,
    int* __restrict__ off_in, int* __restrict__ csr_in,
    const unsigned* __restrict__ staging_out, const int* __restrict__ boff_out,
    int* __restrict__ off_out, int* __restrict__ csr_out) {
  __shared__ int cnt[BSIZE];
  __shared__ int wtot[4];
  int tid = threadIdx.x;
  int b = blockIdx.x;
  int dir = blockIdx.y;
  const unsigned* staging = dir ? staging_out : staging_in;
  const int* boff = dir ? boff_out : boff_in;
  int* off = dir ? off_out : off_in;
  int* csr = dir ? csr_out : csr_in;
  int ebase = boff[b], eend = boff[b + 1];
  int node_base = b << BSHIFT;
  int nnodes = min(BSIZE, N_NODES - node_base);
  cnt[2 * tid] = 0; cnt[2 * tid + 1] = 0;
  __syncthreads();
  for (int e = ebase + tid; e < eend; e += 256)
    atomicAdd(&cnt[staging[e] >> 18], 1);
  __syncthreads();
  int i0 = 2 * tid, i1 = 2 * tid + 1;
  int a0 = cnt[i0], a1 = cnt[i1];
  int pair = a0 + a1;
  int lane = tid & 63, wid = tid >> 6;
  int incl = pair;
#pragma unroll
  for (int o = 1; o < 64; o <<= 1) { int t = __shfl_up(incl, o); if (lane >= o) incl += t; }
  if (lane == 63) wtot[wid] = incl;
  __syncthreads();
  if (tid == 0) { int r = 0; for (int w = 0; w < 4; w++) { int v = wtot[w]; wtot[w] = r; r += v; } }
  __syncthreads();
  int exclp = incl - pair + wtot[wid];
  cnt[i0] = exclp;
  cnt[i1] = exclp + a0;
  __syncthreads();
  for (int i = tid; i < nnodes; i += 256) off[node_base + i] = ebase + cnt[i];
  if (b == KB - 1 && tid == 0) off[N_NODES] = boff[KB];
  __syncthreads();
  for (int e = ebase + tid; e < eend; e += 256) {
    unsigned rec = staging[e];
    int p = atomicAdd(&cnt[rec >> 18], 1);
    csr[ebase + p] = (int)(rec & PAYMASK);
  }
}

// ---------------------------------------------------------------------------
// Pack 32 fp32 channels into 4 bf16 panel arrays (8 ch each, 16 B rows).
// Panels: [out 0-7], [out 8-15], [back 16-23], [back 24-31].
// Each panel is N*8 bf16 = 3.2 MB -> fits a 4 MiB per-XCD L2.
// ---------------------------------------------------------------------------
__device__ __forceinline__ uint4 pack8(const float* a) {
  uint4 t;
  t.x = pack_bf2(a[0], a[1]); t.y = pack_bf2(a[2], a[3]);
  t.z = pack_bf2(a[4], a[5]); t.w = pack_bf2(a[6], a[7]);
  return t;
}
__device__ __forceinline__ void store_panels(
    unsigned short* p0, unsigned short* p1, unsigned short* p2, unsigned short* p3,
    int i, const float* acc) {
  ((uint4*)(p0 + (size_t)i * 8))[0] = pack8(acc + 0);
  ((uint4*)(p1 + (size_t)i * 8))[0] = pack8(acc + 8);
  ((uint4*)(p2 + (size_t)i * 8))[0] = pack8(acc + 16);
  ((uint4*)(p3 + (size_t)i * 8))[0] = pack8(acc + 24);
}

// ---------------------------------------------------------------------------
// A0: x0 = emb[nodes]; y = x0 @ [w0_out | w0_back] -> 4 panels
// ---------------------------------------------------------------------------
__global__ void __launch_bounds__(256) emb_mm_kernel(
    const int* __restrict__ nodes, const float* __restrict__ emb,
    const float* __restrict__ w_out, const float* __restrict__ w_back,
    unsigned short* __restrict__ p0, unsigned short* __restrict__ p1,
    unsigned short* __restrict__ p2, unsigned short* __restrict__ p3) {
  __shared__ float W[CH][CH];
  __shared__ float Esh[NT * CH];
  int tid = threadIdx.x;
  for (int t = tid; t < CH * CH; t += blockDim.x) {
    int k = t >> 5, j = t & 31;
    W[k][j] = (j < 16) ? w_out[k * 16 + j] : w_back[k * 16 + j - 16];
  }
  for (int t = tid; t < NT * CH; t += blockDim.x) Esh[t] = emb[t];
  __syncthreads();
  int i = blockIdx.x * blockDim.x + tid;
  if (i >= N_NODES) return;
  int tn = nodes[i];
  float v[CH];
#pragma unroll
  for (int k = 0; k < CH; k++) v[k] = Esh[tn * CH + k];
  float acc[CH];
#pragma unroll
  for (int j = 0; j < CH; j++) acc[j] = 0.f;
#pragma unroll
  for (int k = 0; k < CH; k++) {
    float vk = v[k];
#pragma unroll
    for (int j = 0; j < CH; j++) acc[j] += vk * W[k][j];
  }
  store_panels(p0, p1, p2, p3, i, acc);
}

// ---------------------------------------------------------------------------
// A: y = relu(bn(x)) @ [w_out | w_back] -> 4 panels
// ---------------------------------------------------------------------------
__global__ void __launch_bounds__(256) bn_relu_mm_kernel(
    const float* __restrict__ xin, const float* __restrict__ stats,
    const float* __restrict__ gamma, const float* __restrict__ beta,
    const float* __restrict__ w_out, const float* __restrict__ w_back,
    unsigned short* __restrict__ p0, unsigned short* __restrict__ p1,
    unsigned short* __restrict__ p2, unsigned short* __restrict__ p3) {
  __shared__ float W[CH][CH];
  __shared__ float sc[CH], sh[CH];
  int tid = threadIdx.x;
  for (int t = tid; t < CH * CH; t += blockDim.x) {
    int k = t >> 5, j = t & 31;
    W[k][j] = (j < 16) ? w_out[k * 16 + j] : w_back[k * 16 + j - 16];
  }
  if (tid < CH) {
    float m  = stats[tid] * (1.0f / N_NODES);
    float s2 = stats[CH + tid] * (1.0f / N_NODES);
    float var = s2 - m * m;
    float scale = gamma[tid] * rsqrtf(var + BN_EPS);
    sc[tid] = scale;
    sh[tid] = beta[tid] - m * scale;
  }
  __syncthreads();
  int i = blockIdx.x * blockDim.x + tid;
  if (i >= N_NODES) return;
  const float4* xp = (const float4*)(xin + (size_t)i * CH);
  float v[CH];
#pragma unroll
  for (int q = 0; q < 8; q++) {
    float4 t = xp[q];
    v[4 * q + 0] = fmaxf(t.x * sc[4 * q + 0] + sh[4 * q + 0], 0.f);
    v[4 * q + 1] = fmaxf(t.y * sc[4 * q + 1] + sh[4 * q + 1], 0.f);
    v[4 * q + 2] = fmaxf(t.z * sc[4 * q + 2] + sh[4 * q + 2], 0.f);
    v[4 * q + 3] = fmaxf(t.w * sc[4 * q + 3] + sh[4 * q + 3], 0.f);
  }
  float acc[CH];
#pragma unroll
  for (int j = 0; j < CH; j++) acc[j] = 0.f;
#pragma unroll
  for (int k = 0; k < CH; k++) {
    float vk = v[k];
#pragma unroll
    for (int j = 0; j < CH; j++) acc[j] += vk * W[k][j];
  }
  store_panels(p0, p1, p2, p3, i, acc);
}

// ---------------------------------------------------------------------------
// B: aggregation over ONE 8-channel panel (16 B rows, L2-resident).
// 2 lanes per node (uint2 = 4 bf16 each); edge loop unrolled x4.
// Grid: ceil(2N/256) = 1563 blocks; guarded tail, no early return
// (all threads reach __syncthreads in the stats path).
// ---------------------------------------------------------------------------
__global__ void __launch_bounds__(256) agg_panel_kernel(
    const unsigned short* __restrict__ y, const float* __restrict__ xres,
    float* __restrict__ out,
    const int* __restrict__ off, const int* __restrict__ csr,
    float* __restrict__ stats, int chanbase) {
  __shared__ float ssum[8], sssq[8];
  int tid = threadIdx.x;
  if (tid < 8) { ssum[tid] = 0.f; sssq[tid] = 0.f; }
  __syncthreads();
  int t = blockIdx.x * 256 + tid;
  bool valid = t < 2 * N_NODES;
  int q = t & 1;            // which uint2 half of the 16 B row
  int i = valid ? (t >> 1) : 0;
  int lo = 0, hi = 0;
  if (valid) { lo = off[i]; hi = off[i + 1]; }
  int q4 = q * 4;           // channel offset within panel
  float a0 = 0.f, a1 = 0.f, a2 = 0.f, a3 = 0.f;
  int e = lo;
  for (; e + 4 <= hi; e += 4) {
    int n0 = csr[e + 0], n1 = csr[e + 1], n2 = csr[e + 2], n3 = csr[e + 3];
    uint2 p0 = *(const uint2*)(y + (size_t)n0 * 8 + q4);
    uint2 p1 = *(const uint2*)(y + (size_t)n1 * 8 + q4);
    uint2 p2 = *(const uint2*)(y + (size_t)n2 * 8 + q4);
    uint2 p3 = *(const uint2*)(y + (size_t)n3 * 8 + q4);
    a0 += BF_LO(p0.x) + BF_LO(p1.x) + BF_LO(p2.x) + BF_LO(p3.x);
    a1 += BF_HI(p0.x) + BF_HI(p1.x) + BF_HI(p2.x) + BF_HI(p3.x);
    a2 += BF_LO(p0.y) + BF_LO(p1.y) + BF_LO(p2.y) + BF_LO(p3.y);
    a3 += BF_HI(p0.y) + BF_HI(p1.y) + BF_HI(p2.y) + BF_HI(p3.y);
  }
  for (; e < hi; e++) {
    int nb = csr[e];
    uint2 p = *(const uint2*)(y + (size_t)nb * 8 + q4);
    a0 += BF_LO(p.x); a1 += BF_HI(p.x);
    a2 += BF_LO(p.y); a3 += BF_HI(p.y);
  }
  if (valid && xres) {
    float4 r = *(const float4*)(xres + (size_t)i * CH + chanbase + q4);
    a0 += r.x; a1 += r.y; a2 += r.z; a3 += r.w;
  }
  if (valid)
    *(float4*)(out + (size_t)i * CH + chanbase + q4) = make_float4(a0, a1, a2, a3);
  if (stats) {
    float s0 = a0 * a0, s1 = a1 * a1, s2 = a2 * a2, s3 = a3 * a3;
    // reduce over 32 node-pairs in the wave, preserving lane parity (q)
#pragma unroll
    for (int o = 32; o >= 2; o >>= 1) {
      a0 += __shfl_down(a0, o); a1 += __shfl_down(a1, o);
      a2 += __shfl_down(a2, o); a3 += __shfl_down(a3, o);
      s0 += __shfl_down(s0, o); s1 += __shfl_down(s1, o);
      s2 += __shfl_down(s2, o); s3 += __shfl_down(s3, o);
    }
    if ((tid & 63) < 2) {   // lane 0 (q=0) and lane 1 (q=1)
      atomicAdd(&ssum[q4 + 0], a0); atomicAdd(&ssum[q4 + 1], a1);
      atomicAdd(&ssum[q4 + 2], a2); atomicAdd(&ssum[q4 + 3], a3);
      atomicAdd(&sssq[q4 + 0], s0); atomicAdd(&sssq[q4 + 1], s1);
      atomicAdd(&sssq[q4 + 2], s2); atomicAdd(&sssq[q4 + 3], s3);
    }
    __syncthreads();
    if (tid < 8) {
      atomicAdd(&stats[chanbase + tid], ssum[tid]);
      atomicAdd(&stats[CH + chanbase + tid], sssq[tid]);
    }
  }
}

// ---------------------------------------------------------------------------
// MLP head, hidden-split x4: block (mb, tile) computes partial score over
// 256 hidden units; atomicAdd into sb (pre-zeroed). bo omitted (cancels
// under log-softmax shift invariance).
// ---------------------------------------------------------------------------
__global__ void __launch_bounds__(256) score_kernel(
    const float* __restrict__ x, const int* __restrict__ indices,
    const int* __restrict__ assignment,
    const float* __restrict__ wh, const float* __restrict__ bh,
    const float* __restrict__ wo,
    float* __restrict__ s, int* __restrict__ seg) {
  __shared__ __align__(16) float s_wh[256][36];
  __shared__ float s_wo[256];
  __shared__ float s_bh[256];
  int tid = threadIdx.x;
  int mb = blockIdx.x >> 2;
  int tile = blockIdx.x & 3;
  int t0 = tile * 256;
  int m = mb * 256 + tid;
  bool valid = m < M_SEL;
  for (int u = tid; u < CH * 256; u += 256) {
    int k = u >> 8, jj = u & 255;
    s_wh[jj][k] = wh[(size_t)k * HID + t0 + jj];
  }
  s_wo[tid] = wo[t0 + tid];
  s_bh[tid] = bh[t0 + tid];
  __syncthreads();
  if (!valid) return;
  int idx = indices[m];
  float a[CH];
  const float4* xp = (const float4*)(x + (size_t)idx * CH);
#pragma unroll
  for (int q = 0; q < 8; q++) {
    float4 t = xp[q];
    a[4 * q + 0] = fmaxf(t.x, 0.f); a[4 * q + 1] = fmaxf(t.y, 0.f);
    a[4 * q + 2] = fmaxf(t.z, 0.f); a[4 * q + 3] = fmaxf(t.w, 0.f);
  }
  float sacc = 0.f;
  for (int jj = 0; jj < 256; jj++) {
    float h = s_bh[jj];
    const float4* wp = (const float4*)&s_wh[jj][0];
#pragma unroll
    for (int q = 0; q < 8; q++) {
      float4 w = wp[q];
      h += a[4 * q] * w.x + a[4 * q + 1] * w.y + a[4 * q + 2] * w.z + a[4 * q + 3] * w.w;
    }
    sacc += fmaxf(h, 0.f) * s_wo[jj];
  }
  atomicAdd(&s[m], sacc);
  if (tile == 0) seg[m] = assignment[idx];
}

// ---------------------------------------------------------------------------
// Segmented log-softmax (seg sorted; one block per segment)
// ---------------------------------------------------------------------------
__device__ __forceinline__ int lower_bound_dev(const int* a, int n, int key) {
  int lo = 0, hi = n;
  while (lo < hi) { int mid = (lo + hi) >> 1; if (a[mid] < key) lo = mid + 1; else hi = mid; }
  return lo;
}

__global__ void __launch_bounds__(256) logsoftmax_kernel(
    const float* __restrict__ s, const int* __restrict__ seg, float* __restrict__ out) {
  __shared__ float red[256];
  __shared__ int bounds[2];
  int tid = threadIdx.x;
  int b = blockIdx.x;
  if (tid == 0) {
    bounds[0] = lower_bound_dev(seg, M_SEL, b);
    bounds[1] = lower_bound_dev(seg, M_SEL, b + 1);
  }
  __syncthreads();
  int lo = bounds[0], hi = bounds[1];
  float mx = -INFINITY;
  for (int i = lo + tid; i < hi; i += 256) mx = fmaxf(mx, s[i]);
  red[tid] = mx; __syncthreads();
  for (int o = 128; o > 0; o >>= 1) { if (tid < o) red[tid] = fmaxf(red[tid], red[tid + o]); __syncthreads(); }
  float mxv = red[0];
  __syncthreads();
  float sum = 0.f;
  for (int i = lo + tid; i < hi; i += 256) sum += expf(s[i] - mxv);
  red[tid] = sum; __syncthreads();
  for (int o = 128; o > 0; o >>= 1) { if (tid < o) red[tid] += red[tid + o]; __syncthreads(); }
  float lse = logf(red[0]);
  for (int i = lo + tid; i < hi; i += 256) out[i] = (s[i] - mxv) - lse;
}

// ---------------------------------------------------------------------------
extern "C" void kernel_launch(void* const* d_in, const int* in_sizes, int n_in,
                              void* d_out, int out_size, void* d_ws, size_t ws_size,
                              hipStream_t stream) {
  const int*   assignment = (const int*)d_in[1];
  const int*   nodes      = (const int*)d_in[2];
  const int*   src        = (const int*)d_in[3];
  const int*   dst        = (const int*)d_in[4];
  const int*   indices    = (const int*)d_in[5];
  const float* emb        = (const float*)d_in[6];
  const float* w0_out     = (const float*)d_in[7];
  const float* w0_back    = (const float*)d_in[8];
  const float* bn1_gamma  = (const float*)d_in[9];
  const float* bn1_beta   = (const float*)d_in[10];
  const float* w1_out     = (const float*)d_in[11];
  const float* w1_back    = (const float*)d_in[12];
  const float* bn2_gamma  = (const float*)d_in[13];
  const float* bn2_beta   = (const float*)d_in[14];
  const float* w2_out     = (const float*)d_in[15];
  const float* w2_back    = (const float*)d_in[16];
  const float* wh         = (const float*)d_in[17];
  const float* bh         = (const float*)d_in[18];
  const float* wo         = (const float*)d_in[19];
  float* out = (float*)d_out;

  char* ws = (char*)d_ws;
  size_t off = 0;
  auto alloc = [&](size_t bytes) {
    char* p = ws + off;
    off = (off + bytes + 255) & ~(size_t)255;
    return p;
  };
  // bcnt_in/bcnt_out contiguous in ONE alloc (single memset covers both;
  // allocator pads to 256B — separate allocs leave poison in the gap)
  int* bcnt_in  = (int*)alloc((size_t)2 * KB * 4); int* bcnt_out = bcnt_in + KB;
  int* boff_in  = (int*)alloc((size_t)(KB + 1) * 4);
  int* boff_out = (int*)alloc((size_t)(KB + 1) * 4);
  int* gcur_in  = (int*)alloc((size_t)KB * 4);
  int* gcur_out = (int*)alloc((size_t)KB * 4);
  int* off_in   = (int*)alloc((size_t)(N_NODES + 1) * 4);
  int* off_out  = (int*)alloc((size_t)(N_NODES + 1) * 4);
  float* stats  = (float*)alloc((size_t)16 * 64 * 4);
  int* csr_in   = (int*)alloc((size_t)N_EDGES * 4);
  int* csr_out  = (int*)alloc((size_t)N_EDGES * 4);
  unsigned short* yp0 = (unsigned short*)alloc((size_t)N_NODES * 8 * 2);  // out ch 0-7
  unsigned short* yp1 = (unsigned short*)alloc((size_t)N_NODES * 8 * 2);  // out ch 8-15
  unsigned short* yp2 = (unsigned short*)alloc((size_t)N_NODES * 8 * 2);  // back ch 16-23
  unsigned short* yp3 = (unsigned short*)alloc((size_t)N_NODES * 8 * 2);  // back ch 24-31
  float* xb = (float*)alloc((size_t)N_NODES * CH * 4);
  float* hb = (float*)alloc((size_t)N_NODES * CH * 4);
  float* sb = (float*)alloc((size_t)M_SEL * 4);
  int* segb = (int*)alloc((size_t)M_SEL * 4);
  // staging aliases xb (consumed by build_kernel before xb is first written)
  unsigned* staging_in  = (unsigned*)xb;
  unsigned* staging_out = (unsigned*)xb + N_EDGES;

  hipMemsetAsync(bcnt_in, 0, (size_t)2 * KB * 4, stream);
  hipMemsetAsync(stats, 0, (size_t)16 * 64 * 4, stream);
  hipMemsetAsync(sb, 0, (size_t)M_SEL * 4, stream);

  bin_count_kernel<<<1024, 256, 0, stream>>>(src, dst, bcnt_in, bcnt_out);
  bucket_scan_kernel<<<1, 256, 0, stream>>>(bcnt_in, boff_in, gcur_in,
                                            bcnt_out, boff_out, gcur_out);
  dim3 gStage((N_EDGES + 4095) / 4096, 2);
  stage_kernel<<<gStage, 256, 0, stream>>>(src, dst, gcur_in, staging_in,
                                           gcur_out, staging_out);
  dim3 gBuild(KB, 2);
  build_kernel<<<gBuild, 256, 0, stream>>>(staging_in, boff_in, off_in, csr_in,
                                           staging_out, boff_out, off_out, csr_out);

  const int gA = (N_NODES + 255) / 256;
  const int gP = (2 * N_NODES + 255) / 256;  // 1563
  auto agg_pass = [&](const float* xres, float* outb, float* st) {
    agg_panel_kernel<<<gP, 256, 0, stream>>>(yp0, xres, outb, off_in, csr_in, st, 0);
    agg_panel_kernel<<<gP, 256, 0, stream>>>(yp1, xres, outb, off_in, csr_in, st, 8);
    agg_panel_kernel<<<gP, 256, 0, stream>>>(yp2, xres, outb, off_out, csr_out, st, 16);
    agg_panel_kernel<<<gP, 256, 0, stream>>>(yp3, xres, outb, off_out, csr_out, st, 24);
  };

  emb_mm_kernel<<<gA, 256, 0, stream>>>(nodes, emb, w0_out, w0_back, yp0, yp1, yp2, yp3);
  agg_pass(nullptr, xb, stats + 0 * 64);
  for (int l = 0; l < NL; l++) {
    bn_relu_mm_kernel<<<gA, 256, 0, stream>>>(xb, stats + (2 * l) * 64,
                                              bn1_gamma + l * CH, bn1_beta + l * CH,
                                              w1_out + l * CH * 16, w1_back + l * CH * 16,
                                              yp0, yp1, yp2, yp3);
    agg_pass(nullptr, hb, stats + (2 * l + 1) * 64);
    bn_relu_mm_kernel<<<gA, 256, 0, stream>>>(hb, stats + (2 * l + 1) * 64,
                                              bn2_gamma + l * CH, bn2_beta + l * CH,
                                              w2_out + l * CH * 16, w2_back + l * CH * 16,
                                              yp0, yp1, yp2, yp3);
    agg_pass(xb, xb, (l < NL - 1) ? (stats + (2 * l + 2) * 64) : nullptr);
  }
  score_kernel<<<4 * ((M_SEL + 255) / 256), 256, 0, stream>>>(
      xb, indices, assignment, wh, bh, wo, sb, segb);
  logsoftmax_kernel<<<NEX, 256, 0, stream>>>(sb, segb, out);
}